// Round 4
// baseline (1209.550 us; speedup 1.0000x reference)
//
#include <hip/hip_runtime.h>
#include <hip/hip_bf16.h>

#define F_IN 128
#define NPB 256      // dst nodes per bucket == gemm1 row tile
#define NPB_SH 8
#define MAXB 512     // static LDS bucket-array size (requires N <= 131072)
#define CHUNK 4096   // edges per bucketing block (391 blocks -> full machine)
#define CAP 5120     // padded per-bucket segment capacity (mean 4096, sigma 64)

typedef __attribute__((ext_vector_type(8))) short short8;   // 8 bf16 (4 VGPRs)
typedef __attribute__((ext_vector_type(4))) float f32x4;    // MFMA accumulator

// ---------------------------------------------------------------- bf16 helpers (storage; math in fp32)

__device__ __forceinline__ float bf2f(unsigned short u) {
    return __uint_as_float(((unsigned int)u) << 16);
}
__device__ __forceinline__ unsigned short f2bf(float f) {
    unsigned int x = __float_as_uint(f);
    x += 0x7FFFu + ((x >> 16) & 1u);   // round-to-nearest-even
    return (unsigned short)(x >> 16);
}
// unpack 8 bf16 (uint4) into v[0..8)
__device__ __forceinline__ void bf8_unpack(uint4 r, float* v) {
    v[0] = __uint_as_float(r.x << 16);
    v[1] = __uint_as_float(r.x & 0xFFFF0000u);
    v[2] = __uint_as_float(r.y << 16);
    v[3] = __uint_as_float(r.y & 0xFFFF0000u);
    v[4] = __uint_as_float(r.z << 16);
    v[5] = __uint_as_float(r.z & 0xFFFF0000u);
    v[6] = __uint_as_float(r.w << 16);
    v[7] = __uint_as_float(r.w & 0xFFFF0000u);
}
// native fp32 atomic add (ds_add_f32 / global_atomic_add_f32, no CAS loop).
// Default float atomicAdd CAS-expands (denormal safety) -> 264 cyc/op (round-3 PMC).
__device__ __forceinline__ void fadd_fast(float* p, float v) {
    unsafeAtomicAdd(p, v);
}

// ---------------------------------------------------------------- weight prep + workspace zeroing
__global__ __launch_bounds__(256) void prep_w_kernel(
    const float* __restrict__ W0, const float* __restrict__ W1,
    unsigned short* __restrict__ W0t, unsigned short* __restrict__ W1t,
    int* __restrict__ gcursor, float* __restrict__ Gbuf,
    int nbucket, int gtot) {
    int t = blockIdx.x * 256 + threadIdx.x;
    int stride = gridDim.x * 256;
    for (int o = t; o < 64 * 128; o += stride) {
        int n = o >> 7, k = o & 127;
        W0t[o] = f2bf(W0[k * 64 + n]);
    }
    for (int o = t; o < 32 * 64; o += stride) {
        int n = o >> 6, k = o & 63;
        W1t[o] = f2bf(W1[k * 32 + n]);
    }
    for (int o = t; o < nbucket; o += stride) gcursor[o] = 0;
    for (int o = t; o < gtot; o += stride) Gbuf[o] = 0.f;
}

// ---------------------------------------------------------------- fused bucketing: hist + reserve + place into padded segments
// tmp[b*CAP + ...] entry: {src | (dst&255)<<17, bits(w)}  (src < 2^17)
// gcursor[b] ends as the bucket's edge count. No dst-sort — scatter kernels
// consume the unsorted segment directly via LDS accumulation.
__global__ __launch_bounds__(1024) void bucket_fused_kernel(
    const int* __restrict__ src, const int* __restrict__ dst,
    const float* __restrict__ ew, int* __restrict__ gcursor,
    int2* __restrict__ tmp, int E, int nbucket) {
    __shared__ int hist[MAXB];
    __shared__ int gbase[MAXB];
    const int tid = threadIdx.x;
    const int e0 = blockIdx.x * CHUNK;
    const int e1 = min(e0 + CHUNK, E);
    for (int b = tid; b < nbucket; b += 1024) hist[b] = 0;
    __syncthreads();
    const int e = e0 + (tid << 2);
    const bool vec = (e + 4 <= e1);
    const int nsc = vec ? 0 : max(0, e1 - e);
    int4 d4 = make_int4(0, 0, 0, 0);
    if (vec) {
        d4 = *(const int4*)(dst + e);
        atomicAdd(&hist[d4.x >> NPB_SH], 1);
        atomicAdd(&hist[d4.y >> NPB_SH], 1);
        atomicAdd(&hist[d4.z >> NPB_SH], 1);
        atomicAdd(&hist[d4.w >> NPB_SH], 1);
    } else {
        for (int j = 0; j < nsc; ++j) {
            int d = dst[e + j];
            ((int*)&d4)[j] = d;
            atomicAdd(&hist[d >> NPB_SH], 1);
        }
    }
    __syncthreads();
    for (int b = tid; b < nbucket; b += 1024) {
        int h = hist[b];
        gbase[b] = (h > 0) ? atomicAdd(&gcursor[b], h) : 0;
        hist[b] = 0;   // reuse as local cursor
    }
    __syncthreads();
    if (vec) {
        int4 s4 = *(const int4*)(src + e);
        float4 w4 = *(const float4*)(ew + e);
        {
            int d = d4.x, b = d >> NPB_SH;
            int r = atomicAdd(&hist[b], 1);
            tmp[(size_t)b * CAP + gbase[b] + r] =
                make_int2(s4.x | ((d & (NPB - 1)) << 17), __float_as_int(w4.x));
        }
        {
            int d = d4.y, b = d >> NPB_SH;
            int r = atomicAdd(&hist[b], 1);
            tmp[(size_t)b * CAP + gbase[b] + r] =
                make_int2(s4.y | ((d & (NPB - 1)) << 17), __float_as_int(w4.y));
        }
        {
            int d = d4.z, b = d >> NPB_SH;
            int r = atomicAdd(&hist[b], 1);
            tmp[(size_t)b * CAP + gbase[b] + r] =
                make_int2(s4.z | ((d & (NPB - 1)) << 17), __float_as_int(w4.z));
        }
        {
            int d = d4.w, b = d >> NPB_SH;
            int r = atomicAdd(&hist[b], 1);
            tmp[(size_t)b * CAP + gbase[b] + r] =
                make_int2(s4.w | ((d & (NPB - 1)) << 17), __float_as_int(w4.w));
        }
    } else {
        for (int j = 0; j < nsc; ++j) {
            int d = ((int*)&d4)[j];
            int b = d >> NPB_SH;
            int r = atomicAdd(&hist[b], 1);
            tmp[(size_t)b * CAP + gbase[b] + r] =
                make_int2(src[e + j] | ((d & (NPB - 1)) << 17), __float_as_int(ew[e + j]));
        }
    }
}

// ---------------------------------------------------------------- gemm1 + dinv (fused): block b = bucket b = rows b*256..+255
// pass 1: dw[d] = sum of in-edge weights (native ds_add_f32) -> dinv
// pass 2: M = bf16(dinv * (X f32 @ W0)) via MFMA, dinv from LDS
__global__ __launch_bounds__(1024) void gemm1_dinv_kernel(
    const float* __restrict__ X, const unsigned short* __restrict__ W0t,
    const int2* __restrict__ tmp, const int* __restrict__ gcursor,
    float* __restrict__ dinv, unsigned short* __restrict__ M, int N) {
    __shared__ unsigned short Bs[64][136];
    __shared__ float dw[256];
    __shared__ float dvs[256];
    const int t = threadIdx.x;
    for (int i = t; i < 64 * 32; i += 1024) {
        int nn = i >> 5, k4 = i & 31;
        ushort4 v = ((const ushort4*)W0t)[i];
        *(ushort4*)&Bs[nn][k4 * 4] = v;
    }
    if (t < 256) dw[t] = 0.f;
    __syncthreads();
    const size_t seg = (size_t)blockIdx.x * CAP;
    const int count = gcursor[blockIdx.x];
    const int pairs = count >> 1;
    for (int i = t; i < pairs; i += 1024) {
        int4 v = *(const int4*)(tmp + seg + 2 * i);
        fadd_fast(&dw[(v.x >> 17) & 255], __int_as_float(v.y));
        fadd_fast(&dw[(v.z >> 17) & 255], __int_as_float(v.w));
    }
    if ((count & 1) && t == 0) {
        int2 e2 = tmp[seg + count - 1];
        fadd_fast(&dw[(e2.x >> 17) & 255], __int_as_float(e2.y));
    }
    __syncthreads();
    if (t < 256) {
        float dv = rsqrtf(fmaxf(1.f + dw[t], 1e-12f));
        dvs[t] = dv;
        int n = (blockIdx.x << NPB_SH) + t;
        if (n < N) dinv[n] = dv;
    }
    __syncthreads();
    const int wave = t >> 6, lane = t & 63;
    const int m = lane & 15, q = lane >> 4;
    const int rowL = wave * 16 + m;
    const int rowA = (blockIdx.x << NPB_SH) + rowL;
    const bool rok = rowA < N;
    const float* xrow = X + (size_t)rowA * 128;
    f32x4 acc[4] = {};
#pragma unroll
    for (int ks = 0; ks < 4; ++ks) {
        int k0 = ks * 32 + q * 8;
        float4 u0 = make_float4(0.f, 0.f, 0.f, 0.f);
        float4 u1 = make_float4(0.f, 0.f, 0.f, 0.f);
        if (rok) {
            u0 = *(const float4*)(xrow + k0);
            u1 = *(const float4*)(xrow + k0 + 4);
        }
        short8 a;
        a[0] = (short)f2bf(u0.x); a[1] = (short)f2bf(u0.y);
        a[2] = (short)f2bf(u0.z); a[3] = (short)f2bf(u0.w);
        a[4] = (short)f2bf(u1.x); a[5] = (short)f2bf(u1.y);
        a[6] = (short)f2bf(u1.z); a[7] = (short)f2bf(u1.w);
#pragma unroll
        for (int ct = 0; ct < 4; ++ct) {
            short8 b = *(const short8*)&Bs[ct * 16 + m][k0];
            acc[ct] = __builtin_amdgcn_mfma_f32_16x16x32_bf16(a, b, acc[ct], 0, 0, 0);
        }
    }
#pragma unroll
    for (int r = 0; r < 4; ++r) {
        int cl = wave * 16 + q * 4 + r;
        int crow = (blockIdx.x << NPB_SH) + cl;
        if (crow < N) {
            float dv = dvs[cl];
#pragma unroll
            for (int ct = 0; ct < 4; ++ct)
                M[(size_t)crow * 64 + ct * 16 + m] = f2bf(acc[ct][r] * dv);
        }
    }
}

// ---------------------------------------------------------------- gemm2 (MFMA): m1p = bf16(dinv * (H1 bf16 @ W1)), K=64, NOUT=32
__global__ __launch_bounds__(256) void gemm2_mfma_kernel(
    const unsigned short* __restrict__ H1, const unsigned short* __restrict__ W1t,
    const float* __restrict__ dinv, unsigned short* __restrict__ M, int N) {
    __shared__ unsigned short Bs[32][72];
    const int tid = threadIdx.x;
    for (int i = tid; i < 32 * 16; i += 256) {
        int n = i >> 4, k4 = i & 15;
        ushort4 v = ((const ushort4*)W1t)[i];
        *(ushort4*)&Bs[n][k4 * 4] = v;
    }
    __syncthreads();
    const int wave = tid >> 6, lane = tid & 63;
    const int m = lane & 15, q = lane >> 4;
    const int rowA = blockIdx.x * 64 + wave * 16 + m;
    const bool rok = rowA < N;
    const short8 az = {0, 0, 0, 0, 0, 0, 0, 0};
    f32x4 acc[2] = {};
#pragma unroll
    for (int ks = 0; ks < 2; ++ks) {
        int k0 = ks * 32 + q * 8;
        short8 a = rok ? *(const short8*)(H1 + (size_t)rowA * 64 + k0) : az;
#pragma unroll
        for (int ct = 0; ct < 2; ++ct) {
            short8 b = *(const short8*)&Bs[ct * 16 + m][k0];
            acc[ct] = __builtin_amdgcn_mfma_f32_16x16x32_bf16(a, b, acc[ct], 0, 0, 0);
        }
    }
#pragma unroll
    for (int r = 0; r < 4; ++r) {
        int crow = blockIdx.x * 64 + wave * 16 + q * 4 + r;
        if (crow < N) {
            float d = dinv[crow];
#pragma unroll
            for (int ct = 0; ct < 2; ++ct)
                M[(size_t)crow * 32 + ct * 16 + m] = f2bf(acc[ct][r] * d);
        }
    }
}

// ---------------------------------------------------------------- pull1 scatter: block b = bucket b; LDS fp32 accum tile [256][64]
// feat index XOR-swizzled by (d&31); native ds_add_f32 scatter.
// H1[n] = bf16(relu(dinv*(acc + M[n]) + b0))
__global__ __launch_bounds__(1024) void pull1_scatter_kernel(
    const int2* __restrict__ tmp, const int* __restrict__ gcursor,
    const unsigned short* __restrict__ M, const float* __restrict__ dinv,
    const float* __restrict__ bias, unsigned short* __restrict__ H1, int N) {
    __shared__ float acc[256 * 64];          // 64 KB
    const int t = threadIdx.x;
    const int n0 = blockIdx.x << NPB_SH;
    const size_t seg = (size_t)blockIdx.x * CAP;
    for (int i = t; i < 256 * 64; i += 1024) acc[i] = 0.f;
    __syncthreads();
    const int count = gcursor[blockIdx.x];
    {
        const int f0 = (t & 7) * 8;          // 8 lanes/edge, 8 feats each
        for (int i = t >> 3; i < count; i += 128) {
            int2 e = tmp[seg + i];
            int s = e.x & 0x1FFFF;
            int d = (e.x >> 17) & 255;
            float w = __int_as_float(e.y);
            uint4 r = *(const uint4*)(M + (size_t)s * 64 + f0);
            float* ap = acc + d * 64;
            const int sw = d & 31;
            fadd_fast(ap + ((f0 + 0) ^ sw), w * __uint_as_float(r.x << 16));
            fadd_fast(ap + ((f0 + 1) ^ sw), w * __uint_as_float(r.x & 0xFFFF0000u));
            fadd_fast(ap + ((f0 + 2) ^ sw), w * __uint_as_float(r.y << 16));
            fadd_fast(ap + ((f0 + 3) ^ sw), w * __uint_as_float(r.y & 0xFFFF0000u));
            fadd_fast(ap + ((f0 + 4) ^ sw), w * __uint_as_float(r.z << 16));
            fadd_fast(ap + ((f0 + 5) ^ sw), w * __uint_as_float(r.z & 0xFFFF0000u));
            fadd_fast(ap + ((f0 + 6) ^ sw), w * __uint_as_float(r.w << 16));
            fadd_fast(ap + ((f0 + 7) ^ sw), w * __uint_as_float(r.w & 0xFFFF0000u));
        }
    }
    __syncthreads();
    const int d = t >> 2;                    // node local; 16 feats/thread
    const int fq = (t & 3) * 16;
    const int n = n0 + d;
    if (n >= N) return;
    const float dv = dinv[n];
    const int sw = d & 31;
    uint4 s0 = *(const uint4*)(M + (size_t)n * 64 + fq);
    uint4 s1 = *(const uint4*)(M + (size_t)n * 64 + fq + 8);
    float sv[16];
    bf8_unpack(s0, sv);
    bf8_unpack(s1, sv + 8);
    const float* ap = acc + d * 64;
    unsigned short o[16];
#pragma unroll
    for (int k = 0; k < 16; ++k) {
        int f = fq + k;
        o[k] = f2bf(fmaxf(fmaf(dv, ap[f ^ sw] + sv[k], bias[f]), 0.f));
    }
    uint4 pk0, pk1;
    pk0.x = (unsigned)o[0]  | ((unsigned)o[1]  << 16);
    pk0.y = (unsigned)o[2]  | ((unsigned)o[3]  << 16);
    pk0.z = (unsigned)o[4]  | ((unsigned)o[5]  << 16);
    pk0.w = (unsigned)o[6]  | ((unsigned)o[7]  << 16);
    pk1.x = (unsigned)o[8]  | ((unsigned)o[9]  << 16);
    pk1.y = (unsigned)o[10] | ((unsigned)o[11] << 16);
    pk1.z = (unsigned)o[12] | ((unsigned)o[13] << 16);
    pk1.w = (unsigned)o[14] | ((unsigned)o[15] << 16);
    *(uint4*)(H1 + (size_t)n * 64 + fq) = pk0;
    *(uint4*)(H1 + (size_t)n * 64 + fq + 8) = pk1;
}

// ---------------------------------------------------------------- pull2 scatter + fused sum-pool: LDS accum [256][32] (relu'd in place)
__global__ __launch_bounds__(1024) void pull2_scatter_pool_kernel(
    const int2* __restrict__ tmp, const int* __restrict__ gcursor,
    const unsigned short* __restrict__ M, const float* __restrict__ dinv,
    const float* __restrict__ bias, const int* __restrict__ ngi,
    float* __restrict__ g, int N) {
    __shared__ float acc[256 * 32];          // 32 KB
    __shared__ int sng[256];
    const int t = threadIdx.x;
    const int n0 = blockIdx.x << NPB_SH;
    const size_t seg = (size_t)blockIdx.x * CAP;
    for (int i = t; i < 256 * 32; i += 1024) acc[i] = 0.f;
    __syncthreads();
    const int count = gcursor[blockIdx.x];
    {
        const int f0 = (t & 3) * 8;          // 4 lanes/edge, 8 feats each
        for (int i = t >> 2; i < count; i += 256) {
            int2 e = tmp[seg + i];
            int s = e.x & 0x1FFFF;
            int d = (e.x >> 17) & 255;
            float w = __int_as_float(e.y);
            uint4 r = *(const uint4*)(M + (size_t)s * 32 + f0);
            float* ap = acc + d * 32;
            const int sw = d & 31;
            fadd_fast(ap + ((f0 + 0) ^ sw), w * __uint_as_float(r.x << 16));
            fadd_fast(ap + ((f0 + 1) ^ sw), w * __uint_as_float(r.x & 0xFFFF0000u));
            fadd_fast(ap + ((f0 + 2) ^ sw), w * __uint_as_float(r.y << 16));
            fadd_fast(ap + ((f0 + 3) ^ sw), w * __uint_as_float(r.y & 0xFFFF0000u));
            fadd_fast(ap + ((f0 + 4) ^ sw), w * __uint_as_float(r.z << 16));
            fadd_fast(ap + ((f0 + 5) ^ sw), w * __uint_as_float(r.z & 0xFFFF0000u));
            fadd_fast(ap + ((f0 + 6) ^ sw), w * __uint_as_float(r.w << 16));
            fadd_fast(ap + ((f0 + 7) ^ sw), w * __uint_as_float(r.w & 0xFFFF0000u));
        }
    }
    __syncthreads();
    {
        const int d = t >> 2;                // relu epilogue: 8 feats/thread
        const int fe = (t & 3) * 8;
        const int n = n0 + d;
        if (n < N) {
            const float dv = dinv[n];
            const int sw = d & 31;
            uint4 s0 = *(const uint4*)(M + (size_t)n * 32 + fe);
            float sv[8];
            bf8_unpack(s0, sv);
            float* ap = acc + d * 32;
#pragma unroll
            for (int k = 0; k < 8; ++k) {
                int f = fe + k;
                int idx = f ^ sw;            // slots are 1:1 per (d,f): in-place safe
                ap[idx] = fmaxf(fmaf(dv, ap[idx] + sv[k], bias[f]), 0.f);
            }
            if ((t & 3) == 0) sng[d] = ngi[n];
        } else if ((t & 3) == 0) {
            sng[d] = -1;
        }
    }
    __syncthreads();
    if (t < 256) {                           // run-length pool: 8 chunks x 32 feats
        const int f = t & 31;
        const int dbase = (t >> 5) * 32;
        float a = 0.f;
        int cg = -1;
        for (int j = 0; j < 32; ++j) {
            int dd = dbase + j;
            int gi = sng[dd];
            if (gi < 0) break;               // invalid nodes only at block tail
            float v = acc[dd * 32 + (f ^ (dd & 31))];
            if (gi != cg) {
                if (cg >= 0) fadd_fast(&g[cg * 32 + f], a);
                cg = gi;
                a = v;
            } else {
                a += v;
            }
        }
        if (cg >= 0) fadd_fast(&g[cg * 32 + f], a);
    }
}

// ---------------------------------------------------------------- MLP head (parallel final reduction)
__global__ __launch_bounds__(128) void mlp_kernel(
    const float* __restrict__ g, const float* __restrict__ Wm1,
    const float* __restrict__ bm1, const float* __restrict__ Wm2,
    const float* __restrict__ bm2, float* __restrict__ out) {
    __shared__ float sg[32];
    __shared__ float red[4];
    int b = blockIdx.x, t = threadIdx.x;
    if (t < 32) sg[t] = g[b * 32 + t];
    __syncthreads();
    float acc = bm1[t];
#pragma unroll
    for (int k = 0; k < 32; ++k) acc = fmaf(sg[k], Wm1[k * 128 + t], acc);
    float h = fmaxf(acc, 0.f);
    float p0 = h * Wm2[t * 2 + 0];
    float p1 = h * Wm2[t * 2 + 1];
#pragma unroll
    for (int off = 32; off >= 1; off >>= 1) {
        p0 += __shfl_xor(p0, off);
        p1 += __shfl_xor(p1, off);
    }
    if ((t & 63) == 0) {
        red[(t >> 6) * 2 + 0] = p0;
        red[(t >> 6) * 2 + 1] = p1;
    }
    __syncthreads();
    if (t < 2) out[b * 2 + t] = bm2[t] + red[t] + red[2 + t];
}

// ---------------------------------------------------------------- launch

extern "C" void kernel_launch(void* const* d_in, const int* in_sizes, int n_in,
                              void* d_out, int out_size, void* d_ws, size_t ws_size,
                              hipStream_t stream) {
    const float* x   = (const float*)d_in[0];
    const int*   ei  = (const int*)d_in[1];
    const float* ew  = (const float*)d_in[2];
    const int*   ngi = (const int*)d_in[3];
    const float* W0  = (const float*)d_in[4];
    const float* b0  = (const float*)d_in[5];
    const float* W1  = (const float*)d_in[6];
    const float* b1  = (const float*)d_in[7];
    const float* Wm1 = (const float*)d_in[8];
    const float* bm1 = (const float*)d_in[9];
    const float* Wm2 = (const float*)d_in[10];
    const float* bm2 = (const float*)d_in[11];
    float* out = (float*)d_out;

    const int N = in_sizes[0] / F_IN;       // 100000 (< 2^17, packing requirement)
    const int E = in_sizes[1] / 2;          // 1600000
    const int G = out_size / 2;             // 1000
    const int* srcp = ei;
    const int* dstp = ei + E;
    const int NBUCKET = (N + NPB - 1) >> NPB_SH;       // 391
    const int NBLK = (E + CHUNK - 1) / CHUNK;          // 391

    // workspace layout (256B-aligned chunks)
    char* wsb = (char*)d_ws;
    size_t off = 0;
    auto alloc = [&](size_t bytes) {
        char* p = wsb + off;
        off += (bytes + 255) & ~(size_t)255;
        return p;
    };
    float* dinv     = (float*)alloc((size_t)N * 4);
    int*   gcursor  = (int*)  alloc((size_t)NBUCKET * 4);
    int2*  tmp      = (int2*) alloc((size_t)NBUCKET * CAP * 8);   // padded bucketed edges
    unsigned short* W0t = (unsigned short*)alloc(64 * 128 * 2);
    unsigned short* W1t = (unsigned short*)alloc(32 * 64 * 2);
    unsigned short* M   = (unsigned short*)alloc((size_t)N * 64 * 2);  // m0' bf16; m1' aliases later
    unsigned short* H1  = (unsigned short*)alloc((size_t)N * 64 * 2);  // h1 bf16
    float* Gbuf     = (float*)alloc((size_t)G * 32 * 4);
    unsigned short* m1p = M;            // N*32 bf16 (m0' dead after pull1)

    // 1. weight prep (+ gcursor/Gbuf zeroing) + fused bucketing
    prep_w_kernel<<<8, 256, 0, stream>>>(W0, W1, W0t, W1t, gcursor, Gbuf, NBUCKET, G * 32);
    bucket_fused_kernel<<<NBLK, 1024, 0, stream>>>(srcp, dstp, ew, gcursor, tmp, E, NBUCKET);

    // 2. layer 1: dinv + m0' = bf16(dinv*(x@W0)) fused; LDS scatter-pull -> h1
    gemm1_dinv_kernel<<<NBUCKET, 1024, 0, stream>>>(x, W0t, tmp, gcursor, dinv, M, N);
    pull1_scatter_kernel<<<NBUCKET, 1024, 0, stream>>>(tmp, gcursor, M, dinv, b0, H1, N);

    // 3. layer 2: m1' = bf16(dinv*(h1@W1)); LDS scatter-pull + fused sum-pool
    gemm2_mfma_kernel<<<(N + 63) / 64, 256, 0, stream>>>(H1, W1t, dinv, m1p, N);
    pull2_scatter_pool_kernel<<<NBUCKET, 1024, 0, stream>>>(tmp, gcursor, m1p, dinv, b1, ngi, Gbuf, N);

    // 4. MLP head
    mlp_kernel<<<G, 128, 0, stream>>>(Gbuf, Wm1, bm1, Wm2, bm2, out);
}

// Round 5
// 250.930 us; speedup vs baseline: 4.8203x; 4.8203x over previous
//
#include <hip/hip_runtime.h>
#include <hip/hip_bf16.h>

#define F_IN 128
#define NPB 256      // dst nodes per bucket
#define NPB_SH 8
#define MAXB 512     // static LDS bucket-array size (requires N <= 131072)
#define CHUNK 4096   // edges per bucketing block (391 blocks -> full machine)
#define CAP 5120     // padded per-bucket segment capacity (mean 4096, sigma 64)

typedef __attribute__((ext_vector_type(8))) short short8;   // 8 bf16 (4 VGPRs)
typedef __attribute__((ext_vector_type(4))) float f32x4;    // MFMA accumulator

// ---------------------------------------------------------------- bf16 helpers (storage; math in fp32)

__device__ __forceinline__ float bf2f(unsigned short u) {
    return __uint_as_float(((unsigned int)u) << 16);
}
__device__ __forceinline__ unsigned short f2bf(float f) {
    unsigned int x = __float_as_uint(f);
    x += 0x7FFFu + ((x >> 16) & 1u);   // round-to-nearest-even
    return (unsigned short)(x >> 16);
}
// unpack 8 bf16 (uint4) and fma into a[0..8)
__device__ __forceinline__ void bf8_fma(float w, uint4 r, float* a) {
    a[0] = fmaf(w, __uint_as_float(r.x << 16), a[0]);
    a[1] = fmaf(w, __uint_as_float(r.x & 0xFFFF0000u), a[1]);
    a[2] = fmaf(w, __uint_as_float(r.y << 16), a[2]);
    a[3] = fmaf(w, __uint_as_float(r.y & 0xFFFF0000u), a[3]);
    a[4] = fmaf(w, __uint_as_float(r.z << 16), a[4]);
    a[5] = fmaf(w, __uint_as_float(r.z & 0xFFFF0000u), a[5]);
    a[6] = fmaf(w, __uint_as_float(r.w << 16), a[6]);
    a[7] = fmaf(w, __uint_as_float(r.w & 0xFFFF0000u), a[7]);
}
// native global fp32 atomic add. NOTE (measured r3/r4): fp32 LDS atomics cost
// ~200cy/lane-op on gfx950 under BOTH atomicAdd and unsafeAtomicAdd — keep fp
// atomics OFF the per-edge path entirely; this helper is for global Gbuf only.
__device__ __forceinline__ void fadd_global(float* p, float v) {
    unsafeAtomicAdd(p, v);
}

// ---------------------------------------------------------------- weight prep + workspace zeroing (folds 2 memset dispatches)
__global__ __launch_bounds__(256) void prep_w_kernel(
    const float* __restrict__ W0, const float* __restrict__ W1,
    unsigned short* __restrict__ W0t, unsigned short* __restrict__ W1t,
    int* __restrict__ gcursor, float* __restrict__ Gbuf,
    int nbucket, int gtot) {
    int t = blockIdx.x * 256 + threadIdx.x;
    int stride = gridDim.x * 256;
    for (int o = t; o < 64 * 128; o += stride) {
        int n = o >> 7, k = o & 127;
        W0t[o] = f2bf(W0[k * 64 + n]);
    }
    for (int o = t; o < 32 * 64; o += stride) {
        int n = o >> 6, k = o & 63;
        W1t[o] = f2bf(W1[k * 32 + n]);
    }
    for (int o = t; o < nbucket; o += stride) gcursor[o] = 0;
    for (int o = t; o < gtot; o += stride) Gbuf[o] = 0.f;
}

// ---------------------------------------------------------------- fused bucketing: hist + reserve + place into padded segments
// tmp[b*CAP + ...] entry: {src | (dst&255)<<17, bits(w)}  (src < 2^17)
// gcursor[b] ends as the bucket's edge count. Int LDS atomics only.
__global__ __launch_bounds__(1024) void bucket_fused_kernel(
    const int* __restrict__ src, const int* __restrict__ dst,
    const float* __restrict__ ew, int* __restrict__ gcursor,
    int2* __restrict__ tmp, int E, int nbucket) {
    __shared__ int hist[MAXB];
    __shared__ int gbase[MAXB];
    const int tid = threadIdx.x;
    const int e0 = blockIdx.x * CHUNK;
    const int e1 = min(e0 + CHUNK, E);
    for (int b = tid; b < nbucket; b += 1024) hist[b] = 0;
    __syncthreads();
    const int e = e0 + (tid << 2);
    const bool vec = (e + 4 <= e1);
    const int nsc = vec ? 0 : max(0, e1 - e);
    int4 d4 = make_int4(0, 0, 0, 0);
    if (vec) {
        d4 = *(const int4*)(dst + e);
        atomicAdd(&hist[d4.x >> NPB_SH], 1);
        atomicAdd(&hist[d4.y >> NPB_SH], 1);
        atomicAdd(&hist[d4.z >> NPB_SH], 1);
        atomicAdd(&hist[d4.w >> NPB_SH], 1);
    } else {
        for (int j = 0; j < nsc; ++j) {
            int d = dst[e + j];
            ((int*)&d4)[j] = d;
            atomicAdd(&hist[d >> NPB_SH], 1);
        }
    }
    __syncthreads();
    for (int b = tid; b < nbucket; b += 1024) {
        int h = hist[b];
        gbase[b] = (h > 0) ? atomicAdd(&gcursor[b], h) : 0;
        hist[b] = 0;   // reuse as local cursor
    }
    __syncthreads();
    if (vec) {
        int4 s4 = *(const int4*)(src + e);
        float4 w4 = *(const float4*)(ew + e);
        {
            int d = d4.x, b = d >> NPB_SH;
            int r = atomicAdd(&hist[b], 1);
            tmp[(size_t)b * CAP + gbase[b] + r] =
                make_int2(s4.x | ((d & (NPB - 1)) << 17), __float_as_int(w4.x));
        }
        {
            int d = d4.y, b = d >> NPB_SH;
            int r = atomicAdd(&hist[b], 1);
            tmp[(size_t)b * CAP + gbase[b] + r] =
                make_int2(s4.y | ((d & (NPB - 1)) << 17), __float_as_int(w4.y));
        }
        {
            int d = d4.z, b = d >> NPB_SH;
            int r = atomicAdd(&hist[b], 1);
            tmp[(size_t)b * CAP + gbase[b] + r] =
                make_int2(s4.z | ((d & (NPB - 1)) << 17), __float_as_int(w4.z));
        }
        {
            int d = d4.w, b = d >> NPB_SH;
            int r = atomicAdd(&hist[b], 1);
            tmp[(size_t)b * CAP + gbase[b] + r] =
                make_int2(s4.w | ((d & (NPB - 1)) << 17), __float_as_int(w4.w));
        }
    } else {
        for (int j = 0; j < nsc; ++j) {
            int d = ((int*)&d4)[j];
            int b = d >> NPB_SH;
            int r = atomicAdd(&hist[b], 1);
            tmp[(size_t)b * CAP + gbase[b] + r] =
                make_int2(src[e + j] | ((d & (NPB - 1)) << 17), __float_as_int(ew[e + j]));
        }
    }
}

// ---------------------------------------------------------------- per-bucket CSR (padded) + rstart/rend + dinv
// Int LDS atomics only. dinv via per-node SERIAL weight sum over the sorted
// range (replaces the fp32 LDS atomicAdd per edge — ~200cy/op, r3/r4 PMC).
__global__ __launch_bounds__(1024) void csr_kernel(
    const int2* __restrict__ tmp, const int* __restrict__ gcursor,
    int2* __restrict__ es, int* __restrict__ rstart, int* __restrict__ rend,
    float* __restrict__ dinv, int N) {
    __shared__ int cnt[256];
    __shared__ int off[256];
    __shared__ int cur[256];
    const int t = threadIdx.x;
    const int n0 = blockIdx.x << NPB_SH;
    const size_t seg = (size_t)blockIdx.x * CAP;
    if (t < 256) cnt[t] = 0;
    __syncthreads();
    const int count = gcursor[blockIdx.x];
    const int pairs = count >> 1;
    for (int i = t; i < pairs; i += 1024) {
        int4 v = *(const int4*)(tmp + seg + 2 * i);
        atomicAdd(&cnt[v.x >> 17], 1);
        atomicAdd(&cnt[v.z >> 17], 1);
    }
    if ((count & 1) && t == 0) {
        int2 e2 = tmp[seg + count - 1];
        atomicAdd(&cnt[e2.x >> 17], 1);
    }
    __syncthreads();
    int myc = 0, excl = 0;
    if (t < 256) {
        myc = cnt[t];
        off[t] = myc;
    }
    __syncthreads();
    for (int o = 1; o < 256; o <<= 1) {
        int x = 0;
        if (t >= o && t < 256) x = off[t - o];
        __syncthreads();
        if (t < 256) off[t] += x;
        __syncthreads();
    }
    if (t < 256) {
        excl = off[t] - myc;
        cur[t] = excl;
        int n = n0 + t;
        if (n < N) {
            rstart[n] = (int)seg + excl;
            rend[n] = (int)seg + excl + myc;
        }
    }
    __syncthreads();
    for (int i = t; i < pairs; i += 1024) {
        int4 v = *(const int4*)(tmp + seg + 2 * i);
        int d0 = v.x >> 17, d1 = v.z >> 17;
        int r0 = atomicAdd(&cur[d0], 1);
        es[seg + r0] = make_int2(v.x & 0x1FFFF, v.y);
        int r1 = atomicAdd(&cur[d1], 1);
        es[seg + r1] = make_int2(v.z & 0x1FFFF, v.w);
    }
    if ((count & 1) && t == 0) {
        int2 e2 = tmp[seg + count - 1];
        int d = e2.x >> 17;
        int r = atomicAdd(&cur[d], 1);
        es[seg + r] = make_int2(e2.x & 0x1FFFF, e2.y);
    }
    __syncthreads();   // barrier waitcnt drains the es writes to L2
    if (t < 256) {
        int n = n0 + t;
        if (n < N) {
            float s = 0.f;
            const int2* ep = es + seg + excl;
            for (int j = 0; j < myc; ++j) s += __int_as_float(ep[j].y);
            dinv[n] = rsqrtf(fmaxf(1.f + s, 1e-12f));
        }
    }
}

// ---------------------------------------------------------------- gemm1 (MFMA): M = bf16(dinv * (X f32 @ W0)), K=128, NOUT=64
__global__ __launch_bounds__(256) void gemm1_mfma_kernel(
    const float* __restrict__ X, const unsigned short* __restrict__ W0t,
    const float* __restrict__ dinv, unsigned short* __restrict__ M, int N) {
    __shared__ unsigned short Bs[64][136];
    const int tid = threadIdx.x;
    for (int i = tid; i < 64 * 32; i += 256) {
        int n = i >> 5, k4 = i & 31;
        ushort4 v = ((const ushort4*)W0t)[i];
        *(ushort4*)&Bs[n][k4 * 4] = v;
    }
    __syncthreads();
    const int wave = tid >> 6, lane = tid & 63;
    const int m = lane & 15, q = lane >> 4;
    const int rowA = blockIdx.x * 64 + wave * 16 + m;
    const bool rok = rowA < N;
    const float* xrow = X + (size_t)rowA * 128;
    f32x4 acc[4] = {};
#pragma unroll
    for (int ks = 0; ks < 4; ++ks) {
        int k0 = ks * 32 + q * 8;
        float4 u0 = make_float4(0.f, 0.f, 0.f, 0.f);
        float4 u1 = make_float4(0.f, 0.f, 0.f, 0.f);
        if (rok) {
            u0 = *(const float4*)(xrow + k0);
            u1 = *(const float4*)(xrow + k0 + 4);
        }
        short8 a;
        a[0] = (short)f2bf(u0.x); a[1] = (short)f2bf(u0.y);
        a[2] = (short)f2bf(u0.z); a[3] = (short)f2bf(u0.w);
        a[4] = (short)f2bf(u1.x); a[5] = (short)f2bf(u1.y);
        a[6] = (short)f2bf(u1.z); a[7] = (short)f2bf(u1.w);
#pragma unroll
        for (int ct = 0; ct < 4; ++ct) {
            short8 b = *(const short8*)&Bs[ct * 16 + m][k0];
            acc[ct] = __builtin_amdgcn_mfma_f32_16x16x32_bf16(a, b, acc[ct], 0, 0, 0);
        }
    }
#pragma unroll
    for (int r = 0; r < 4; ++r) {
        int crow = blockIdx.x * 64 + wave * 16 + q * 4 + r;
        if (crow < N) {
            float d = dinv[crow];
#pragma unroll
            for (int ct = 0; ct < 4; ++ct)
                M[(size_t)crow * 64 + ct * 16 + m] = f2bf(acc[ct][r] * d);
        }
    }
}

// ---------------------------------------------------------------- gemm2 (MFMA): m1p = bf16(dinv * (H1 bf16 @ W1)), K=64, NOUT=32
__global__ __launch_bounds__(256) void gemm2_mfma_kernel(
    const unsigned short* __restrict__ H1, const unsigned short* __restrict__ W1t,
    const float* __restrict__ dinv, unsigned short* __restrict__ M, int N) {
    __shared__ unsigned short Bs[32][72];
    const int tid = threadIdx.x;
    for (int i = tid; i < 32 * 16; i += 256) {
        int n = i >> 4, k4 = i & 15;
        ushort4 v = ((const ushort4*)W1t)[i];
        *(ushort4*)&Bs[n][k4 * 4] = v;
    }
    __syncthreads();
    const int wave = tid >> 6, lane = tid & 63;
    const int m = lane & 15, q = lane >> 4;
    const int rowA = blockIdx.x * 64 + wave * 16 + m;
    const bool rok = rowA < N;
    const short8 az = {0, 0, 0, 0, 0, 0, 0, 0};
    f32x4 acc[2] = {};
#pragma unroll
    for (int ks = 0; ks < 2; ++ks) {
        int k0 = ks * 32 + q * 8;
        short8 a = rok ? *(const short8*)(H1 + (size_t)rowA * 64 + k0) : az;
#pragma unroll
        for (int ct = 0; ct < 2; ++ct) {
            short8 b = *(const short8*)&Bs[ct * 16 + m][k0];
            acc[ct] = __builtin_amdgcn_mfma_f32_16x16x32_bf16(a, b, acc[ct], 0, 0, 0);
        }
    }
#pragma unroll
    for (int r = 0; r < 4; ++r) {
        int crow = blockIdx.x * 64 + wave * 16 + q * 4 + r;
        if (crow < N) {
            float d = dinv[crow];
#pragma unroll
            for (int ct = 0; ct < 2; ++ct)
                M[(size_t)crow * 32 + ct * 16 + m] = f2bf(acc[ct][r] * d);
        }
    }
}

// ---------------------------------------------------------------- pull1: 2 nodes/wave x 4 contiguous chains x 8 lanes(16B), 4 edges in flight
// H1[node] = bf16( relu( dinv*(m'[node] + sum w*m'[src]) + b0 ) )
__global__ __launch_bounds__(256) void pull1_kernel(
    const int* __restrict__ rstart, const int* __restrict__ rend,
    const int2* __restrict__ es, const unsigned short* __restrict__ M,
    const float* __restrict__ dinv, const float* __restrict__ bias,
    unsigned short* __restrict__ H1, int N) {
    const int lane = threadIdx.x & 63;
    const int wave = threadIdx.x >> 6;
    const int nd = lane >> 5;              // node within wave (0..1)
    const int node = blockIdx.x * 8 + wave * 2 + nd;
    if (node >= N) return;                 // shuffles stay within 32-lane half
    const int c = lane & 7;                // feature octet (8 bf16 = 16 B)
    const int q = (lane >> 3) & 3;         // chain 0..3
    float acc[8] = {0.f, 0.f, 0.f, 0.f, 0.f, 0.f, 0.f, 0.f};
    if (q == 0) {                           // self-loop counted once
        uint4 r = *(const uint4*)(M + (size_t)node * 64 + c * 8);
        bf8_fma(1.f, r, acc);
    }
    const int b = rstart[node], e = rend[node];
    const int len = e - b;
    const int base = len >> 2, rem = len & 3;
    int p = b + q * base + min(q, rem);
    const int pe = p + base + (q < rem ? 1 : 0);
    for (; p + 4 <= pe; p += 4) {           // 4 edges in flight per chain
        int4 v0 = *(const int4*)(es + p);
        int4 v1 = *(const int4*)(es + p + 2);
        uint4 r0 = *(const uint4*)(M + (size_t)v0.x * 64 + c * 8);
        uint4 r1 = *(const uint4*)(M + (size_t)v0.z * 64 + c * 8);
        uint4 r2 = *(const uint4*)(M + (size_t)v1.x * 64 + c * 8);
        uint4 r3 = *(const uint4*)(M + (size_t)v1.z * 64 + c * 8);
        bf8_fma(__int_as_float(v0.y), r0, acc);
        bf8_fma(__int_as_float(v0.w), r1, acc);
        bf8_fma(__int_as_float(v1.y), r2, acc);
        bf8_fma(__int_as_float(v1.w), r3, acc);
    }
    if (p + 2 <= pe) {
        int4 v = *(const int4*)(es + p);
        uint4 r0 = *(const uint4*)(M + (size_t)v.x * 64 + c * 8);
        uint4 r1 = *(const uint4*)(M + (size_t)v.z * 64 + c * 8);
        bf8_fma(__int_as_float(v.y), r0, acc);
        bf8_fma(__int_as_float(v.w), r1, acc);
        p += 2;
    }
    if (p < pe) {
        int2 ed = es[p];
        uint4 r = *(const uint4*)(M + (size_t)ed.x * 64 + c * 8);
        bf8_fma(__int_as_float(ed.y), r, acc);
    }
#pragma unroll
    for (int off = 8; off <= 16; off <<= 1)   // reduce across 4 chains
#pragma unroll
        for (int k = 0; k < 8; ++k) acc[k] += __shfl_xor(acc[k], off);
    if (q == 0) {
        float d = dinv[node];
        const float* bp = bias + c * 8;
        float4 b0v = *(const float4*)(bp);
        float4 b1v = *(const float4*)(bp + 4);
        unsigned short o[8];
        o[0] = f2bf(fmaxf(fmaf(d, acc[0], b0v.x), 0.f));
        o[1] = f2bf(fmaxf(fmaf(d, acc[1], b0v.y), 0.f));
        o[2] = f2bf(fmaxf(fmaf(d, acc[2], b0v.z), 0.f));
        o[3] = f2bf(fmaxf(fmaf(d, acc[3], b0v.w), 0.f));
        o[4] = f2bf(fmaxf(fmaf(d, acc[4], b1v.x), 0.f));
        o[5] = f2bf(fmaxf(fmaf(d, acc[5], b1v.y), 0.f));
        o[6] = f2bf(fmaxf(fmaf(d, acc[6], b1v.z), 0.f));
        o[7] = f2bf(fmaxf(fmaf(d, acc[7], b1v.w), 0.f));
        uint4 pk;
        pk.x = (unsigned int)o[0] | ((unsigned int)o[1] << 16);
        pk.y = (unsigned int)o[2] | ((unsigned int)o[3] << 16);
        pk.z = (unsigned int)o[4] | ((unsigned int)o[5] << 16);
        pk.w = (unsigned int)o[6] | ((unsigned int)o[7] << 16);
        *(uint4*)(H1 + (size_t)node * 64 + c * 8) = pk;
    }
}

// ---------------------------------------------------------------- pull2 + fused sum-pool: 4 nodes/wave x 4 contiguous chains x 4 lanes(16B), 4 edges in flight
__global__ __launch_bounds__(256) void pull2_pool_kernel(
    const int* __restrict__ rstart, const int* __restrict__ rend,
    const int2* __restrict__ es, const unsigned short* __restrict__ M,
    const float* __restrict__ dinv, const float* __restrict__ bias,
    const int* __restrict__ ngi, float* __restrict__ g, int N) {
    __shared__ float4 sh[16][8];
    __shared__ int sgx[16];
    const int t = threadIdx.x;
    const int lane = t & 63;
    const int nl = t >> 4;                 // node local 0..15 (= wave*4 + nd)
    const int node = blockIdx.x * 16 + nl;
    const int c = lane & 3;                // feature octet (8 bf16 of 32)
    const int q = (lane >> 2) & 3;         // chain 0..3
    const bool valid = node < N;
    float acc[8] = {0.f, 0.f, 0.f, 0.f, 0.f, 0.f, 0.f, 0.f};
    if (valid) {
        if (q == 0) {
            uint4 r = *(const uint4*)(M + (size_t)node * 32 + c * 8);
            bf8_fma(1.f, r, acc);
        }
        const int b = rstart[node], e = rend[node];
        const int len = e - b;
        const int base = len >> 2, rem = len & 3;
        int p = b + q * base + min(q, rem);
        const int pe = p + base + (q < rem ? 1 : 0);
        for (; p + 4 <= pe; p += 4) {       // 4 edges in flight per chain
            int4 v0 = *(const int4*)(es + p);
            int4 v1 = *(const int4*)(es + p + 2);
            uint4 r0 = *(const uint4*)(M + (size_t)v0.x * 32 + c * 8);
            uint4 r1 = *(const uint4*)(M + (size_t)v0.z * 32 + c * 8);
            uint4 r2 = *(const uint4*)(M + (size_t)v1.x * 32 + c * 8);
            uint4 r3 = *(const uint4*)(M + (size_t)v1.z * 32 + c * 8);
            bf8_fma(__int_as_float(v0.y), r0, acc);
            bf8_fma(__int_as_float(v0.w), r1, acc);
            bf8_fma(__int_as_float(v1.y), r2, acc);
            bf8_fma(__int_as_float(v1.w), r3, acc);
        }
        if (p + 2 <= pe) {
            int4 v = *(const int4*)(es + p);
            uint4 r0 = *(const uint4*)(M + (size_t)v.x * 32 + c * 8);
            uint4 r1 = *(const uint4*)(M + (size_t)v.z * 32 + c * 8);
            bf8_fma(__int_as_float(v.y), r0, acc);
            bf8_fma(__int_as_float(v.w), r1, acc);
            p += 2;
        }
        if (p < pe) {
            int2 ed = es[p];
            uint4 r = *(const uint4*)(M + (size_t)ed.x * 32 + c * 8);
            bf8_fma(__int_as_float(ed.y), r, acc);
        }
#pragma unroll
        for (int off = 4; off <= 8; off <<= 1)   // reduce across 4 chains
#pragma unroll
            for (int k = 0; k < 8; ++k) acc[k] += __shfl_xor(acc[k], off);
    }
    if (q == 0) {                          // 4 lanes per node hold the result
        float4 o0 = make_float4(0.f, 0.f, 0.f, 0.f);
        float4 o1 = make_float4(0.f, 0.f, 0.f, 0.f);
        if (valid) {
            float d = dinv[node];
            const float* bp = bias + c * 8;
            float4 b0v = *(const float4*)(bp);
            float4 b1v = *(const float4*)(bp + 4);
            o0.x = fmaxf(fmaf(d, acc[0], b0v.x), 0.f);
            o0.y = fmaxf(fmaf(d, acc[1], b0v.y), 0.f);
            o0.z = fmaxf(fmaf(d, acc[2], b0v.z), 0.f);
            o0.w = fmaxf(fmaf(d, acc[3], b0v.w), 0.f);
            o1.x = fmaxf(fmaf(d, acc[4], b1v.x), 0.f);
            o1.y = fmaxf(fmaf(d, acc[5], b1v.y), 0.f);
            o1.z = fmaxf(fmaf(d, acc[6], b1v.z), 0.f);
            o1.w = fmaxf(fmaf(d, acc[7], b1v.w), 0.f);
        }
        sh[nl][c * 2] = o0;
        sh[nl][c * 2 + 1] = o1;
        if (c == 0) sgx[nl] = valid ? ngi[node] : -1;
    }
    __syncthreads();
    if (t < 8) {                           // run-length combine across the block's 16 nodes
        int cc = t;
        float4 a = make_float4(0.f, 0.f, 0.f, 0.f);
        int cg = -1;
        for (int i = 0; i < 16; ++i) {
            int gi = sgx[i];
            if (gi < 0) continue;
            if (gi != cg) {
                if (cg >= 0) {
                    float* gp = g + cg * 32 + cc * 4;
                    fadd_global(gp + 0, a.x); fadd_global(gp + 1, a.y);
                    fadd_global(gp + 2, a.z); fadd_global(gp + 3, a.w);
                }
                cg = gi;
                a = sh[i][cc];
            } else {
                float4 tv = sh[i][cc];
                a.x += tv.x; a.y += tv.y; a.z += tv.z; a.w += tv.w;
            }
        }
        if (cg >= 0) {
            float* gp = g + cg * 32 + cc * 4;
            fadd_global(gp + 0, a.x); fadd_global(gp + 1, a.y);
            fadd_global(gp + 2, a.z); fadd_global(gp + 3, a.w);
        }
    }
}

// ---------------------------------------------------------------- MLP head (parallel final reduction)
__global__ __launch_bounds__(128) void mlp_kernel(
    const float* __restrict__ g, const float* __restrict__ Wm1,
    const float* __restrict__ bm1, const float* __restrict__ Wm2,
    const float* __restrict__ bm2, float* __restrict__ out) {
    __shared__ float sg[32];
    __shared__ float red[4];
    int b = blockIdx.x, t = threadIdx.x;
    if (t < 32) sg[t] = g[b * 32 + t];
    __syncthreads();
    float acc = bm1[t];
#pragma unroll
    for (int k = 0; k < 32; ++k) acc = fmaf(sg[k], Wm1[k * 128 + t], acc);
    float h = fmaxf(acc, 0.f);
    float p0 = h * Wm2[t * 2 + 0];
    float p1 = h * Wm2[t * 2 + 1];
#pragma unroll
    for (int off = 32; off >= 1; off >>= 1) {
        p0 += __shfl_xor(p0, off);
        p1 += __shfl_xor(p1, off);
    }
    if ((t & 63) == 0) {
        red[(t >> 6) * 2 + 0] = p0;
        red[(t >> 6) * 2 + 1] = p1;
    }
    __syncthreads();
    if (t < 2) out[b * 2 + t] = bm2[t] + red[t] + red[2 + t];
}

// ---------------------------------------------------------------- launch

extern "C" void kernel_launch(void* const* d_in, const int* in_sizes, int n_in,
                              void* d_out, int out_size, void* d_ws, size_t ws_size,
                              hipStream_t stream) {
    const float* x   = (const float*)d_in[0];
    const int*   ei  = (const int*)d_in[1];
    const float* ew  = (const float*)d_in[2];
    const int*   ngi = (const int*)d_in[3];
    const float* W0  = (const float*)d_in[4];
    const float* b0  = (const float*)d_in[5];
    const float* W1  = (const float*)d_in[6];
    const float* b1  = (const float*)d_in[7];
    const float* Wm1 = (const float*)d_in[8];
    const float* bm1 = (const float*)d_in[9];
    const float* Wm2 = (const float*)d_in[10];
    const float* bm2 = (const float*)d_in[11];
    float* out = (float*)d_out;

    const int N = in_sizes[0] / F_IN;       // 100000 (< 2^17, packing requirement)
    const int E = in_sizes[1] / 2;          // 1600000
    const int G = out_size / 2;             // 1000
    const int* srcp = ei;
    const int* dstp = ei + E;
    const int NBUCKET = (N + NPB - 1) >> NPB_SH;       // 391
    const int NBLK = (E + CHUNK - 1) / CHUNK;          // 391

    // workspace layout (256B-aligned chunks)
    char* wsb = (char*)d_ws;
    size_t off = 0;
    auto alloc = [&](size_t bytes) {
        char* p = wsb + off;
        off += (bytes + 255) & ~(size_t)255;
        return p;
    };
    float* dinv     = (float*)alloc((size_t)N * 4);
    int*   gcursor  = (int*)  alloc((size_t)NBUCKET * 4);
    int*   rstart   = (int*)  alloc((size_t)N * 4);
    int*   rend     = (int*)  alloc((size_t)N * 4);
    int2*  tmp      = (int2*) alloc((size_t)NBUCKET * CAP * 8);   // padded bucketed edges
    int2*  es       = (int2*) alloc((size_t)NBUCKET * CAP * 8);   // padded CSR edges
    unsigned short* W0t = (unsigned short*)alloc(64 * 128 * 2);
    unsigned short* W1t = (unsigned short*)alloc(32 * 64 * 2);
    unsigned short* M   = (unsigned short*)alloc((size_t)N * 64 * 2);  // m0' bf16; m1' aliases later
    unsigned short* H1  = (unsigned short*)alloc((size_t)N * 64 * 2);  // h1 bf16
    float* Gbuf     = (float*)alloc((size_t)G * 32 * 4);
    unsigned short* m1p = M;            // N*32 bf16 (m0' dead after pull1)

    // 1. weight prep (+ gcursor/Gbuf zeroing) + fused bucketing + padded CSR (int atomics only)
    prep_w_kernel<<<8, 256, 0, stream>>>(W0, W1, W0t, W1t, gcursor, Gbuf, NBUCKET, G * 32);
    bucket_fused_kernel<<<NBLK, 1024, 0, stream>>>(srcp, dstp, ew, gcursor, tmp, E, NBUCKET);
    csr_kernel<<<NBUCKET, 1024, 0, stream>>>(tmp, gcursor, es, rstart, rend, dinv, N);

    // 2. layer 1: m0' = bf16(dinv*(x@W0)) via MFMA; pull (4-deep chains) -> h1 bf16
    gemm1_mfma_kernel<<<(N + 63) / 64, 256, 0, stream>>>(x, W0t, dinv, M, N);
    pull1_kernel<<<(N + 7) / 8, 256, 0, stream>>>(rstart, rend, es, M, dinv, b0, H1, N);

    // 3. layer 2: m1' = bf16(dinv*(h1@W1)) via MFMA; pull (4-deep) + fused sum-pool
    gemm2_mfma_kernel<<<(N + 63) / 64, 256, 0, stream>>>(H1, W1t, dinv, m1p, N);
    pull2_pool_kernel<<<(N + 15) / 16, 256, 0, stream>>>(rstart, rend, es, m1p, dinv, b1, ngi, Gbuf, N);

    // 4. MLP head
    mlp_kernel<<<G, 128, 0, stream>>>(Gbuf, Wm1, bm1, Wm2, bm2, out);
}